// Round 1
// baseline (227.727 us; speedup 1.0000x reference)
//
#include <hip/hip_runtime.h>
#include <cstdint>

#define NB 128
#define NT 1024
#define NC 128
#define NL 128
#define NS 257
#define EPSF 1e-7f
#define CHUNK 32
#define LN2F 0.69314718055994530942f
#define NEGL2 -1.442695e30f   // so that value * ln2 ~= -1e30 (reference NEG)

__device__ __forceinline__ float fast_exp2(float x) { return __builtin_amdgcn_exp2f(x); }
__device__ __forceinline__ float fast_log2(float x) { return __builtin_amdgcn_logf(x); }

// One wave (64 lanes) per batch element.
// Lane l owns extended states 4l..4l+3; lane 63 additionally owns state 256.
// alpha[4l+i] = m_i * 2^e  (per-lane scale offset e, exact bookkeeping).
__global__ __launch_bounds__(64, 1)
void ctc_fwd_kernel(const int* __restrict__ y_true,
                    const float* __restrict__ y_pred,
                    const int* __restrict__ input_len,
                    const int* __restrict__ label_len,
                    float* __restrict__ out)
{
    __shared__ float rows[2][CHUNK * NC];   // 2 x 16 KB double-buffered prob rows
    __shared__ float lg_alpha[NS + 3];      // final log2(alpha) per state

    const int b    = blockIdx.x;
    const int lane = threadIdx.x;           // 0..63

    const float* __restrict__ base = y_pred + (size_t)b * NT * NC;

    int Tn = input_len[b];
    Tn = Tn < 0 ? 0 : (Tn > NT ? NT : Tn);

    // ---- labels / skip flags (ext[s]=blank for even s, y[(s-1)/2] for odd s) ----
    const int* __restrict__ yrow = y_true + b * NL;
    const int y0v = yrow[2 * lane]     & (NC - 1);   // label index for state 4l+1 (j=2l)
    const int y1v = yrow[2 * lane + 1] & (NC - 1);   // label index for state 4l+3 (j=2l+1)
    const int yp  = __shfl_up(y1v, 1, 64);           // y[2l-1]
    const bool skip1 = (lane > 0) && (y0v != yp);    // skip into state 4l+1
    const bool skip3 = (y1v != y0v);                 // skip into state 4l+3
    const bool isl0  = (lane == 0);
    const bool isl63 = (lane == 63);

    float m0 = isl0 ? 1.0f : 0.0f;   // alpha0: state 0 = 1 (log 0), rest 0 (log -inf)
    float m1 = 0.f, m2 = 0.f, m3 = 0.f, m4 = 0.f;   // m4 = state 256 (lane 63 only)
    float e  = 0.f;                  // per-lane log2 scale

    // ---- stage chunk 0 into LDS ----
    float4 stage[16];
    {
        const float4* g = (const float4*)base;
        #pragma unroll
        for (int i = 0; i < 16; ++i) stage[i] = g[i * 64 + lane];
        float4* l = (float4*)&rows[0][0];
        #pragma unroll
        for (int i = 0; i < 16; ++i) l[i * 64 + lane] = stage[i];
    }
    __syncthreads();

    auto step = [&](const float* __restrict__ prow, int r) {
        // neighbor value + scale (from previous timestep's state)
        float shm3 = __shfl_up(m3, 1, 64);
        float she  = __shfl_up(e,  1, 64);
        // scale adoption: a lane with no mass takes its neighbor's scale so
        // the first incoming pm1 is not flushed by a stale offset
        float s4 = (m0 + m1) + (m2 + m3);
        if (isl63) s4 += m4;
        e = (s4 == 0.0f && !isl0) ? she : e;
        float d = she - e;
        d = fminf(fmaxf(d, -126.0f), 120.0f);
        float pm1 = shm3 * fast_exp2(d);   // alpha[4l-1] in this lane's scale
        pm1 = isl0 ? 0.0f : pm1;

        float pB = prow[NC - 1] + EPSF;    // blank prob (same-address broadcast)
        float p0 = prow[y0v]    + EPSF;
        float p1 = prow[y1v]    + EPSF;

        float t1 = skip1 ? pm1 : 0.0f;
        float t3 = skip3 ? m1  : 0.0f;

        float n4 = pB * (m4 + m3);               // state 256 (blank)
        float n3 = p1 * ((m3 + m2) + t3);        // state 4l+3 (label 2l+1)
        float n2 = pB * (m2 + m1);               // state 4l+2 (blank)
        float n1 = p0 * ((m1 + m0) + t1);        // state 4l+1 (label 2l)
        float n0 = pB * (m0 + pm1);              // state 4l   (blank)
        m0 = n0; m1 = n1; m2 = n2; m3 = n3; m4 = n4;

        // per-lane rescale every 4 steps (no cross-lane reduction needed)
        if ((r & 3) == 3) {
            float mx = fmaxf(fmaxf(m0, m1), fmaxf(m2, m3));
            mx = fmaxf(mx, isl63 ? m4 : 0.0f);
            mx = fmaxf(mx, 1e-37f);
            float il  = fast_log2(mx);
            float inv = __builtin_amdgcn_rcpf(mx);
            e += il;
            m0 *= inv; m1 *= inv; m2 *= inv; m3 *= inv; m4 *= inv;
        }
    };

    const int nchunks = (Tn + CHUNK - 1) / CHUNK;
    for (int k = 0; k < nchunks; ++k) {
        const int t0 = k * CHUNK;
        const bool more = (t0 + CHUNK) < NT;   // rows exist for the next chunk
        if (more) {
            const float4* g = (const float4*)(base + (size_t)(t0 + CHUNK) * NC);
            #pragma unroll
            for (int i = 0; i < 16; ++i) stage[i] = g[i * 64 + lane];
        }
        const float* __restrict__ buf = &rows[k & 1][0];
        int tend = Tn - t0; tend = tend > CHUNK ? CHUNK : tend;
        if (tend == CHUNK) {
            #pragma unroll 4
            for (int r = 0; r < CHUNK; ++r) step(buf + r * NC, r);
        } else {
            for (int r = 0; r < tend; ++r) step(buf + r * NC, r);
        }
        if (more) {
            float4* l = (float4*)&rows[(k + 1) & 1][0];
            #pragma unroll
            for (int i = 0; i < 16; ++i) l[i * 64 + lane] = stage[i];
        }
        __syncthreads();
    }

    // ---- epilogue: log2(alpha) for every state, then final 2-way logaddexp ----
    lg_alpha[4 * lane + 0] = (m0 > 0.f) ? (e + fast_log2(m0)) : NEGL2;
    lg_alpha[4 * lane + 1] = (m1 > 0.f) ? (e + fast_log2(m1)) : NEGL2;
    lg_alpha[4 * lane + 2] = (m2 > 0.f) ? (e + fast_log2(m2)) : NEGL2;
    lg_alpha[4 * lane + 3] = (m3 > 0.f) ? (e + fast_log2(m3)) : NEGL2;
    if (isl63) lg_alpha[256] = (m4 > 0.f) ? (e + fast_log2(m4)) : NEGL2;
    __syncthreads();

    if (lane == 0) {
        int lab = label_len[b];
        lab = lab < 0 ? 0 : (lab > NL ? NL : lab);
        const int i_last = 2 * lab;
        const int i_prev = i_last > 0 ? i_last - 1 : 0;
        float A  = lg_alpha[i_last];
        float Bv = lg_alpha[i_prev];
        float mx = fmaxf(A, Bv);
        float r;
        if (mx < -1.0e29f) {
            r = mx;                         // both unreachable -> ~ -1e30 like reference
        } else {
            float s = fast_exp2(A - mx) + fast_exp2(Bv - mx);
            r = mx + fast_log2(s);
        }
        out[b] = -r * LN2F;
    }
}

extern "C" void kernel_launch(void* const* d_in, const int* in_sizes, int n_in,
                              void* d_out, int out_size, void* d_ws, size_t ws_size,
                              hipStream_t stream) {
    const int*   y_true    = (const int*)d_in[0];
    const float* y_pred    = (const float*)d_in[1];
    const int*   input_len = (const int*)d_in[2];
    const int*   label_len = (const int*)d_in[3];
    float* outp = (float*)d_out;
    ctc_fwd_kernel<<<dim3(NB), dim3(64), 0, stream>>>(y_true, y_pred, input_len, label_len, outp);
}